// Round 9
// baseline (397.382 us; speedup 1.0000x reference)
//
#include <hip/hip_runtime.h>

#define SS 512
#define BB 512
#define TT 64
#define FSTRIDE ((size_t)BB * TT)

typedef float float2v __attribute__((ext_vector_type(2)));

// element q (0..63) of a float2v[32] register array (q must be compile-time)
#define EL(A, q) ((((q) & 1) == 0) ? (A)[(q) >> 1].x : (A)[(q) >> 1].y)

// One wave (64 lanes) per batch element; lane == target tag j.
// Zero barriers. Single-wave lockstep makes the per-step LDS publish/broadcast
// safe (same-wave DS ops are pipe-ordered; validated R6-R8 absmax=0).
// R9: sched_barrier(0) pins the next-step broadcast ds_reads ABOVE the index
// scan, so their ~250cy latency hides under the scan instead of being exposed
// (R7/R8 the allocator sank them below, VGPR=132 signature).
__global__ __launch_bounds__(TT, 1) void viterbi_wave(
    const float* __restrict__ feats,   // (S,B,T)
    const float* __restrict__ mask,    // (B,S)
    const float* __restrict__ startt,  // (T,)
    const float* __restrict__ endt,    // (T,)
    const float* __restrict__ trans,   // (T,T)
    int* __restrict__ out)             // (B,S)
{
    __shared__ float vbuf[TT];
    __shared__ unsigned char hist[(SS - 1) * TT];

    const int b    = blockIdx.x;
    const int lane = threadIdx.x;      // target tag j

    // transitions column T[i][lane] as pairs over i (64 VGPRs, loop-invariant)
    float2v tc2[32];
#pragma unroll
    for (int q = 0; q < 32; ++q) {
        float2v t;
        t.x = trans[(2 * q) * TT + lane];
        t.y = trans[(2 * q + 1) * TT + lane];
        tc2[q] = t;
    }

    // len = sum(mask[b]) (exact 0/1 adds), uniform after butterfly
    float msum = 0.f;
#pragma unroll
    for (int k = 0; k < 8; ++k) msum += mask[b * SS + lane + 64 * k];
#pragma unroll
    for (int off = 1; off < 64; off <<= 1) msum += __shfl_xor(msum, off);
    const int len = (int)(msum + 0.5f);

    // v0 = start + feats[0]; publish and broadcast-load into vA
    float vlast = startt[lane] + feats[(size_t)b * TT + lane];
    vbuf[lane] = vlast;
    float2v vA[32], vB[32];

    auto loadv = [&](float2v(&dst)[32]) {
#pragma unroll
        for (int q = 0; q < 16; ++q) {
            float4 f = *(const float4*)&vbuf[4 * q];   // ds_read_b128 broadcast
            float2v a; a.x = f.x; a.y = f.y; dst[2 * q]     = a;
            float2v c; c.x = f.z; c.y = f.w; dst[2 * q + 1] = c;
        }
    };
    loadv(vA);

    const float* fb = feats + (size_t)b * TT + lane;
    unsigned hoff = lane;

    // One Viterbi step. cur = current v replicated; sc = (v+T)+e in place
    // (exact reference association); exact max via fmaxf tree; publish new v;
    // issue next broadcast reads; PIN them; then first-max index scan runs
    // while the reads are in flight.
    auto vstep = [&](float2v(&cur)[32], float2v(&nxt)[32], float e) {
        float2v ee; ee.x = e; ee.y = e;
#pragma unroll
        for (int q = 0; q < 32; ++q) cur[q] = (cur[q] + tc2[q]) + ee;

        // exact max tree: 64 -> 22 -> 8 -> 3 -> 1 (fp max is rounding-free)
        float l1[22];
#pragma unroll
        for (int k = 0; k < 21; ++k)
            l1[k] = fmaxf(fmaxf(EL(cur, 3 * k), EL(cur, 3 * k + 1)), EL(cur, 3 * k + 2));
        l1[21] = EL(cur, 63);
        float l2[8];
#pragma unroll
        for (int k = 0; k < 7; ++k)
            l2[k] = fmaxf(fmaxf(l1[3 * k], l1[3 * k + 1]), l1[3 * k + 2]);
        l2[7] = l1[21];
        float l3a = fmaxf(fmaxf(l2[0], l2[1]), l2[2]);
        float l3b = fmaxf(fmaxf(l2[3], l2[4]), l2[5]);
        float best = fmaxf(fmaxf(l3a, l3b), fmaxf(l2[6], l2[7]));

        // publish v_new; immediately issue next step's broadcast reads
        vbuf[lane] = best;
        loadv(nxt);
        // PIN: nothing below may move above; the ds_reads may not sink below.
        __builtin_amdgcn_sched_barrier(0);

        // first-max index: 8 chains, descending k, last writer = smallest
        // index; '==' vs the exact max == reference first-occurrence argmax.
        int i0 = 64, i1 = 64, i2 = 64, i3 = 64, i4 = 64, i5 = 64, i6 = 64, i7 = 64;
#pragma unroll
        for (int k = 7; k >= 0; --k) {
            if (EL(cur, k)      == best) i0 = k;
            if (EL(cur, 8 + k)  == best) i1 = 8 + k;
            if (EL(cur, 16 + k) == best) i2 = 16 + k;
            if (EL(cur, 24 + k) == best) i3 = 24 + k;
            if (EL(cur, 32 + k) == best) i4 = 32 + k;
            if (EL(cur, 40 + k) == best) i5 = 40 + k;
            if (EL(cur, 48 + k) == best) i6 = 48 + k;
            if (EL(cur, 56 + k) == best) i7 = 56 + k;
        }
        // chains cover disjoint ascending ranges -> plain min merge
        int bi = min(min(min(i0, i1), min(i2, i3)), min(min(i4, i5), min(i6, i7)));

        hist[hoff] = (unsigned char)bi;
        hoff += TT;
        vlast = best;
    };

    // emissions: 8-deep chunked prefetch (static reg indexing)
    float ec[8], en[8];
#pragma unroll
    for (int u = 0; u < 8; ++u) ec[u] = fb[(size_t)(1 + u) * FSTRIDE];

    int s = 1;
    while (s + 8 <= len) {
#pragma unroll
        for (int u = 0; u < 8; ++u) {
            int sn = s + 8 + u; if (sn > SS - 1) sn = SS - 1;
            en[u] = fb[(size_t)sn * FSTRIDE];
        }
        vstep(vA, vB, ec[0]);
        vstep(vB, vA, ec[1]);
        vstep(vA, vB, ec[2]);
        vstep(vB, vA, ec[3]);
        vstep(vA, vB, ec[4]);
        vstep(vB, vA, ec[5]);
        vstep(vA, vB, ec[6]);
        vstep(vB, vA, ec[7]);
#pragma unroll
        for (int u = 0; u < 8; ++u) ec[u] = en[u];
        s += 8;
    }
    // tail (s ≡ 1 mod 8, so parity of u selects the buffer)
    if (s + 0 < len) vstep(vA, vB, ec[0]);
    if (s + 1 < len) vstep(vB, vA, ec[1]);
    if (s + 2 < len) vstep(vA, vB, ec[2]);
    if (s + 3 < len) vstep(vB, vA, ec[3]);
    if (s + 4 < len) vstep(vA, vB, ec[4]);
    if (s + 5 < len) vstep(vB, vA, ec[5]);
    if (s + 6 < len) vstep(vA, vB, ec[6]);

    // final argmax over tags (lex first-max butterfly)
    float fv = vlast + endt[lane];
    int bix = lane;
#pragma unroll
    for (int off = 1; off < 64; off <<= 1) {
        float ov = __shfl_xor(fv, off);
        int   oi = __shfl_xor(bix, off);
        if (ov > fv || (ov == fv && oi < bix)) { fv = ov; bix = oi; }
    }
    int cur = bix;                      // uniform across wave
    int* ob = out + (size_t)b * SS;

    if (lane == 0) { ob[SS - 1] = cur; ob[len - 1] = cur; }

    // zeros for masked region s in [len, S-2]
    for (int s2 = len + lane; s2 < SS - 1; s2 += TT) ob[s2] = 0;

    // backtrace: row-load + ds_bpermute chase (pipelined by 1)
    int rowb = hist[(len - 2) * TT + lane];
    for (int s2 = len - 2; s2 >= 0; --s2) {
        int rown = (s2 > 0) ? hist[(s2 - 1) * TT + lane] : 0;
        cur = __builtin_amdgcn_ds_bpermute(cur << 2, rowb);  // = hist[s2][cur]
        if (lane == 0) ob[s2] = cur;
        rowb = rown;
    }
}

extern "C" void kernel_launch(void* const* d_in, const int* in_sizes, int n_in,
                              void* d_out, int out_size, void* d_ws, size_t ws_size,
                              hipStream_t stream) {
    const float* feats  = (const float*)d_in[0];
    const float* mask   = (const float*)d_in[1];
    const float* startt = (const float*)d_in[2];
    const float* endt   = (const float*)d_in[3];
    const float* trans  = (const float*)d_in[4];
    int* out = (int*)d_out;

    viterbi_wave<<<dim3(BB), dim3(TT), 0, stream>>>(
        feats, mask, startt, endt, trans, out);
}

// Round 10
// 257.255 us; speedup vs baseline: 1.5447x; 1.5447x over previous
//
#include <hip/hip_runtime.h>

#define SS 512
#define BB 512
#define TT 64
#define NTHREADS 256
#define FSTRIDE ((size_t)BB * TT)

// DPP quad_perm helpers: exchange within groups of 4 lanes (1 VALU op, no LDS).
// xor1 -> [1,0,3,2] = 0xB1 ; xor2 -> [2,3,0,1] = 0x4E
template <int CTRL>
__device__ __forceinline__ float dppf(float x) {
    return __int_as_float(__builtin_amdgcn_mov_dpp(__float_as_int(x), CTRL, 0xF, 0xF, true));
}
template <int CTRL>
__device__ __forceinline__ int dppi(int x) {
    return __builtin_amdgcn_mov_dpp(x, CTRL, 0xF, 0xF, true);
}

// Raw barrier: drain LDS ops (cross-wave vbuf visibility) but do NOT drain
// vmcnt -- emissions prefetch loads stay in flight across the barrier.
__device__ __forceinline__ void barrier_lgkm() {
    asm volatile("s_waitcnt lgkmcnt(0)\n\ts_barrier" ::: "memory");
}

// One block per batch element. 4 waves; tid -> (j = tid>>2, li = tid&3).
// Lane (j,li) covers source tags i in [li*16, li*16+16).
// R10: one-time per-block phase stagger. Two blocks co-resident on a CU are
// launched in phase and have identical per-step timing -> their barrier
// stalls ALIGN and the CU idles through every LDS/barrier round trip.
// A hashed 0-15 x ~70cy start offset anti-phases co-residents so one block's
// compute fills the other's stall.
__global__ __launch_bounds__(NTHREADS) void viterbi_fused(
    const float* __restrict__ feats,   // (S,B,T)
    const float* __restrict__ mask,    // (B,S)
    const float* __restrict__ startt,  // (T,)
    const float* __restrict__ endt,    // (T,)
    const float* __restrict__ trans,   // (T,T)
    int* __restrict__ out)             // (B,S)
{
    __shared__ float vbuf[2][TT];
    __shared__ unsigned char hist[SS - 1][TT];
    __shared__ float redbuf[4];
    __shared__ int lenSh;

    const int b   = blockIdx.x;
    const int tid = threadIdx.x;
    const int j   = tid >> 2;
    const int li  = tid & 3;
    const int base_i = li * 16;
    const int wid = tid >> 6;
    const int lane = tid & 63;

    // ---- transitions column slice into registers (issue early) ----
    float tcr[16];
#pragma unroll
    for (int k = 0; k < 16; ++k) tcr[k] = trans[(base_i + k) * TT + j];

    // ---- init: score0 = start + feats[0] ----
    if (tid < TT) vbuf[0][tid] = startt[tid] + feats[(size_t)b * TT + tid];

    // ---- sequence length: sum of mask row ----
    float msum = mask[b * SS + tid] + mask[b * SS + 256 + tid];
#pragma unroll
    for (int off = 1; off < 64; off <<= 1) msum += __shfl_xor(msum, off);
    if (lane == 0) redbuf[wid] = msum;
    __syncthreads();
    if (tid == 0) {
        float t = redbuf[0] + redbuf[1] + redbuf[2] + redbuf[3];
        lenSh = (int)(t + 0.5f);
    }
    __syncthreads();

    const int len = lenSh;
    int p = 0;

    // ---- phase stagger: hashed 0-15 sleep units (~70cy each), one time ----
    {
        const int nsl = (int)((blockIdx.x * 2654435761u) >> 28);
        for (int k = 0; k < nsl; ++k) __builtin_amdgcn_s_sleep(1);
    }

    const float* fb = feats + (size_t)b * TT + j;   // per-thread emis pointer

    // step body: scores, 16-candidate argmax (first-index tie rule), DPP
    // combine across the 4 lanes of j, vbuf/hist update, raw barrier.
    auto body = [&](float e, int s) {
        float v[16];
#pragma unroll
        for (int q = 0; q < 4; ++q) {
            float4 t4 = *(const float4*)&vbuf[p][base_i + q * 4];
            v[q * 4 + 0] = t4.x; v[q * 4 + 1] = t4.y;
            v[q * 4 + 2] = t4.z; v[q * 4 + 3] = t4.w;
        }
        float sc[16];
#pragma unroll
        for (int k = 0; k < 16; ++k) sc[k] = (v[k] + tcr[k]) + e;

        // 4 independent chains + tree merge; strict '>' + lower-index-on-tie
        // everywhere == sequential first-max scan, bit-exact.
        float c0 = sc[0];  int x0 = 0;
        float c1 = sc[4];  int x1 = 4;
        float c2 = sc[8];  int x2 = 8;
        float c3 = sc[12]; int x3 = 12;
#pragma unroll
        for (int k = 1; k < 4; ++k) {
            if (sc[k]      > c0) { c0 = sc[k];      x0 = k; }
            if (sc[4 + k]  > c1) { c1 = sc[4 + k];  x1 = 4 + k; }
            if (sc[8 + k]  > c2) { c2 = sc[8 + k];  x2 = 8 + k; }
            if (sc[12 + k] > c3) { c3 = sc[12 + k]; x3 = 12 + k; }
        }
        if (c1 > c0) { c0 = c1; x0 = x1; }
        if (c3 > c2) { c2 = c3; x2 = x3; }
        if (c2 > c0) { c0 = c2; x0 = x2; }
        float best = c0;
        int   bi   = base_i + x0;

        {
            float ov = dppf<0xB1>(best);
            int   oi = dppi<0xB1>(bi);
            if (ov > best || (ov == best && oi < bi)) { best = ov; bi = oi; }
            ov = dppf<0x4E>(best);
            oi = dppi<0x4E>(bi);
            if (ov > best || (ov == best && oi < bi)) { best = ov; bi = oi; }
        }

        if (li == 0) {
            vbuf[p ^ 1][j] = best;               // mask==1 here: new_v = best
            hist[s - 1][j] = (unsigned char)bi;
        }
        barrier_lgkm();
        p ^= 1;
    };

    // ---- emissions: chunked prefetch, 8 steps ahead, static reg indexing ----
    float ec[8], en[8];
#pragma unroll
    for (int u = 0; u < 8; ++u) {
        int sn = 1 + u; if (sn > SS - 1) sn = SS - 1;
        ec[u] = fb[(size_t)sn * FSTRIDE];
    }

    int s = 1;
    while (s + 8 <= len) {
#pragma unroll
        for (int u = 0; u < 8; ++u) {
            int sn = s + 8 + u; if (sn > SS - 1) sn = SS - 1;
            en[u] = fb[(size_t)sn * FSTRIDE];
        }
#pragma unroll
        for (int u = 0; u < 8; ++u) body(ec[u], s + u);
#pragma unroll
        for (int u = 0; u < 8; ++u) ec[u] = en[u];
        s += 8;
    }
    // tail (< 8 steps), uniform branches
#pragma unroll
    for (int u = 0; u < 7; ++u) {
        if (s + u < len) body(ec[u], s + u);
    }

    // ---- final argmax + backtrace (wave 0) ----
    if (tid < TT) {
        float fv = vbuf[p][tid] + endt[tid];
        int bix = tid;
#pragma unroll
        for (int off = 1; off < 64; off <<= 1) {
            float ov = __shfl_xor(fv, off);
            int   oi = __shfl_xor(bix, off);
            if (ov > fv || (ov == fv && oi < bix)) { fv = ov; bix = oi; }
        }
        if (tid == 0) {
            int* ob = out + (size_t)b * SS;
            int cur = bix;
            ob[SS - 1] = cur;      // decode[S-1] = last_path always
            ob[len - 1] = cur;     // position len-1 = last_path
            for (int s2 = len - 2; s2 >= 0; --s2) {
                cur = hist[s2][cur];
                ob[s2] = cur;
            }
        }
    }

    // zeros for masked region s in [len, S-2]
    for (int s2 = len + tid; s2 < SS - 1; s2 += NTHREADS)
        out[(size_t)b * SS + s2] = 0;
}

extern "C" void kernel_launch(void* const* d_in, const int* in_sizes, int n_in,
                              void* d_out, int out_size, void* d_ws, size_t ws_size,
                              hipStream_t stream) {
    const float* feats  = (const float*)d_in[0];
    const float* mask   = (const float*)d_in[1];
    const float* startt = (const float*)d_in[2];
    const float* endt   = (const float*)d_in[3];
    const float* trans  = (const float*)d_in[4];
    int* out = (int*)d_out;

    viterbi_fused<<<dim3(BB), dim3(NTHREADS), 0, stream>>>(
        feats, mask, startt, endt, trans, out);
}